// Round 15
// baseline (627.442 us; speedup 1.0000x reference)
//
#include <hip/hip_runtime.h>
#include <hip/hip_bf16.h>

#define NREL 3
#define EMB 32
#define HID 64

typedef __attribute__((ext_vector_type(8))) short short8_t;
typedef __attribute__((ext_vector_type(4))) short short4_t;
typedef __attribute__((ext_vector_type(4))) float f32x4;

__device__ inline short f2bf(float v) {
  __hip_bfloat16 b = __float2bfloat16(v);
  short s;
  __builtin_memcpy(&s, &b, 2);
  return s;
}
__device__ inline float bf2f(short s) {
  __hip_bfloat16 b;
  __builtin_memcpy(&b, &s, 2);
  return __bfloat162float(b);
}
__device__ inline void split8(const float* v, short8_t* h, short8_t* l) {
#pragma unroll
  for (int i = 0; i < 8; i++) {
    short hh = f2bf(v[i]);
    (*h)[i] = hh;
    (*l)[i] = f2bf(v[i] - bf2f(hh));
  }
}

// ---- fused prep: embedding (hi/lo planes) + edge histogram + weight prep ----
__global__ __launch_bounds__(256) void prep_k(
    const int* __restrict__ sid, const int* __restrict__ cid, const int* __restrict__ pid,
    const float* __restrict__ se, const float* __restrict__ ce, const float* __restrict__ pe,
    short* __restrict__ xh, short* __restrict__ xl,
    const int* __restrict__ dst, const int* __restrict__ et, int* __restrict__ icnt,
    const float* __restrict__ root1, const float* __restrict__ W1,
    const float* __restrict__ root2, const float* __restrict__ W2,
    short* __restrict__ w1h, short* __restrict__ w1l,
    short* __restrict__ w2h, short* __restrict__ w2l, int N, int E) {
  int i = blockIdx.x * 256 + threadIdx.x;
  if (i < N * 8) {
    int n = i >> 3, cg = i & 7;
    const float4 a = *(const float4*)&se[sid[n] * EMB + cg * 4];
    const float4 b = *(const float4*)&ce[cid[n] * EMB + cg * 4];
    const float4 c = *(const float4*)&pe[pid[n] * EMB + cg * 4];
    float v[4];
    v[0] = a.x + b.x + c.x; v[1] = a.y + b.y + c.y;
    v[2] = a.z + b.z + c.z; v[3] = a.w + b.w + c.w;
    short4_t h, l;
#pragma unroll
    for (int j = 0; j < 4; j++) {
      short hh = f2bf(v[j]);
      h[j] = hh;
      l[j] = f2bf(v[j] - bf2f(hh));
    }
    *(short4_t*)&xh[(size_t)n * EMB + cg * 4] = h;
    *(short4_t*)&xl[(size_t)n * EMB + cg * 4] = l;
  }
  if (i < E) atomicAdd(&icnt[et[i] * N + dst[i]], 1);
  if (i < 64 * 128) {
    int k = i >> 6, n = i & 63;
    float v = (k < EMB) ? root1[k * 64 + n] : W1[(k - EMB) * 64 + n];
    short h = f2bf(v);
    w1h[n * 128 + k] = h;
    w1l[n * 128 + k] = f2bf(v - bf2f(h));
  }
  if (i < 64 * 256) {
    int k = i >> 6, n = i & 63;
    float v = (k < HID) ? root2[k * 64 + n] : W2[(k - HID) * 64 + n];
    short h = f2bf(v);
    w2h[n * 256 + k] = h;
    w2l[n * 256 + k] = f2bf(v - bf2f(h));
  }
}

__global__ __launch_bounds__(256) void scan1_k(const int* __restrict__ icnt,
                                               int* __restrict__ psum, int M) {
  int base = blockIdx.x * 1024 + threadIdx.x * 4;
  int s = 0;
#pragma unroll
  for (int j = 0; j < 4; j++) {
    int i = base + j;
    if (i < M) s += icnt[i];
  }
  __shared__ int tmp[256];
  tmp[threadIdx.x] = s;
  __syncthreads();
  for (int off = 128; off > 0; off >>= 1) {
    if (threadIdx.x < off) tmp[threadIdx.x] += tmp[threadIdx.x + off];
    __syncthreads();
  }
  if (threadIdx.x == 0) psum[blockIdx.x] = tmp[0];
}

__global__ __launch_bounds__(256) void scan2_k(int* __restrict__ psum, int P) {
  __shared__ int tmp[256];
  __shared__ int carry_s;
  if (threadIdx.x == 0) carry_s = 0;
  __syncthreads();
  for (int base = 0; base < P; base += 256) {
    int i = base + threadIdx.x;
    int v = (i < P) ? psum[i] : 0;
    tmp[threadIdx.x] = v;
    __syncthreads();
    for (int off = 1; off < 256; off <<= 1) {
      int u = (threadIdx.x >= off) ? tmp[threadIdx.x - off] : 0;
      __syncthreads();
      tmp[threadIdx.x] += u;
      __syncthreads();
    }
    int carry = carry_s;
    if (i < P) psum[i] = carry + tmp[threadIdx.x] - v;
    __syncthreads();
    if (threadIdx.x == 0) carry_s = carry + tmp[255];
    __syncthreads();
  }
}

__global__ __launch_bounds__(256) void scan3_k(const int* __restrict__ icnt,
                                               const int* __restrict__ psum,
                                               int* __restrict__ offs,
                                               int* __restrict__ cursor, int M) {
  int base = blockIdx.x * 1024 + threadIdx.x * 4;
  int v[4];
  int s = 0;
#pragma unroll
  for (int j = 0; j < 4; j++) {
    int i = base + j;
    v[j] = (i < M) ? icnt[i] : 0;
    s += v[j];
  }
  __shared__ int tmp[256];
  tmp[threadIdx.x] = s;
  __syncthreads();
  for (int off = 1; off < 256; off <<= 1) {
    int u = (threadIdx.x >= off) ? tmp[threadIdx.x - off] : 0;
    __syncthreads();
    tmp[threadIdx.x] += u;
    __syncthreads();
  }
  int run = psum[blockIdx.x] + tmp[threadIdx.x] - s;
#pragma unroll
  for (int j = 0; j < 4; j++) {
    int i = base + j;
    if (i < M) {
      offs[i] = run;
      cursor[i] = run;
      run += v[j];
    }
  }
}

__global__ __launch_bounds__(256) void scatter_k(const int* __restrict__ src,
                                                 const int* __restrict__ dst,
                                                 const int* __restrict__ et,
                                                 int* __restrict__ cursor,
                                                 int* __restrict__ csr, int E, int N) {
  int e = blockIdx.x * 256 + threadIdx.x;
  if (e >= E) return;
  int p = atomicAdd(&cursor[et[e] * N + dst[e]], 1);
  csr[p] = src[e];
}

// ====== dedicated high-occupancy gather kernels ======
// thread = (segment, 16B col-slice). No MFMA state -> tiny VGPR -> ~8 waves/SIMD.
// l1: rows of xh (32 cols, 4 slices). agg out = bf16 hi mean.
__global__ __launch_bounds__(256) void l1agg_k(
    const short* __restrict__ xh, const int* __restrict__ offs, const int* __restrict__ icnt,
    const int* __restrict__ csr, short* __restrict__ agg, int SEG) {
  int tid = blockIdx.x * 256 + threadIdx.x;
  if (tid >= SEG * 4) return;
  int q = tid & 3, seg = tid >> 2;
  int beg = offs[seg], len = icnt[seg];
  // idx burst (csr padded: unconditional reads safe)
  int i0 = csr[beg], i1 = csr[beg + 1], i2 = csr[beg + 2], i3 = csr[beg + 3];
  short8_t v0 = {0,0,0,0,0,0,0,0}, v1 = v0, v2 = v0, v3 = v0;
  if (0 < len) v0 = *(const short8_t*)&xh[(size_t)i0 * EMB + q * 8];
  if (1 < len) v1 = *(const short8_t*)&xh[(size_t)i1 * EMB + q * 8];
  if (2 < len) v2 = *(const short8_t*)&xh[(size_t)i2 * EMB + q * 8];
  if (3 < len) v3 = *(const short8_t*)&xh[(size_t)i3 * EMB + q * 8];
  float a[8];
#pragma unroll
  for (int i = 0; i < 8; i++) a[i] = bf2f(v0[i]) + bf2f(v1[i]) + bf2f(v2[i]) + bf2f(v3[i]);
  for (int j = 4; j < len; j++) {
    int id = csr[beg + j];
    short8_t v = *(const short8_t*)&xh[(size_t)id * EMB + q * 8];
#pragma unroll
    for (int i = 0; i < 8; i++) a[i] += bf2f(v[i]);
  }
  float inv = 1.f / fmaxf((float)len, 1.f);
  short8_t o;
#pragma unroll
  for (int i = 0; i < 8; i++) o[i] = f2bf(a[i] * inv);
  *(short8_t*)&agg[(size_t)seg * EMB + q * 8] = o;
}

// l2: rows of h1h (64 cols, 8 slices)
__global__ __launch_bounds__(256) void l2agg_k(
    const short* __restrict__ h1h, const int* __restrict__ offs, const int* __restrict__ icnt,
    const int* __restrict__ csr, short* __restrict__ agg, int SEG) {
  int tid = blockIdx.x * 256 + threadIdx.x;
  if (tid >= SEG * 8) return;
  int q = tid & 7, seg = tid >> 3;
  int beg = offs[seg], len = icnt[seg];
  int i0 = csr[beg], i1 = csr[beg + 1], i2 = csr[beg + 2], i3 = csr[beg + 3];
  short8_t v0 = {0,0,0,0,0,0,0,0}, v1 = v0, v2 = v0, v3 = v0;
  if (0 < len) v0 = *(const short8_t*)&h1h[(size_t)i0 * HID + q * 8];
  if (1 < len) v1 = *(const short8_t*)&h1h[(size_t)i1 * HID + q * 8];
  if (2 < len) v2 = *(const short8_t*)&h1h[(size_t)i2 * HID + q * 8];
  if (3 < len) v3 = *(const short8_t*)&h1h[(size_t)i3 * HID + q * 8];
  float a[8];
#pragma unroll
  for (int i = 0; i < 8; i++) a[i] = bf2f(v0[i]) + bf2f(v1[i]) + bf2f(v2[i]) + bf2f(v3[i]);
  for (int j = 4; j < len; j++) {
    int id = csr[beg + j];
    short8_t v = *(const short8_t*)&h1h[(size_t)id * HID + q * 8];
#pragma unroll
    for (int i = 0; i < 8; i++) a[i] += bf2f(v[i]);
  }
  float inv = 1.f / fmaxf((float)len, 1.f);
  short8_t o;
#pragma unroll
  for (int i = 0; i < 8; i++) o[i] = f2bf(a[i] * inv);
  *(short8_t*)&agg[(size_t)seg * HID + q * 8] = o;
}

// ====== layer-1 GEMM: streaming A (xh/xl self + agg1 means) + split-bf16 MFMA -> h1 hi/lo ======
__global__ __launch_bounds__(256) void l1gemm_k(
    const short* __restrict__ xh, const short* __restrict__ xl, const short* __restrict__ agg,
    const short* __restrict__ wth, const short* __restrict__ wtl,
    const float* __restrict__ bias, short* __restrict__ h1h, short* __restrict__ h1l, int N) {
  const int t = threadIdx.x;
  const int lane = t & 63, w = t >> 6;
  const int m_ = lane & 15, q = lane >> 4;
  const int n0 = blockIdx.x * 64 + w * 16;
  int n = n0 + m_;
  if (n >= N) n = N - 1;

  short8_t ah0 = *(const short8_t*)&xh[(size_t)n * EMB + q * 8];
  short8_t al0 = *(const short8_t*)&xl[(size_t)n * EMB + q * 8];
  short8_t ahn[NREL];
#pragma unroll
  for (int r = 0; r < NREL; r++)
    ahn[r] = *(const short8_t*)&agg[((size_t)r * N + n) * EMB + q * 8];

  f32x4 acc[4];
#pragma unroll
  for (int i = 0; i < 4; i++) acc[i] = (f32x4){0.f, 0.f, 0.f, 0.f};
#pragma unroll
  for (int tt = 0; tt < 4; tt++) {
    const size_t wrow = (size_t)(16 * tt + m_) * 128;
#pragma unroll
    for (int g = 0; g < 4; g++) {
      short8_t bh = *(const short8_t*)&wth[wrow + g * 32 + q * 8];
      short8_t bl = *(const short8_t*)&wtl[wrow + g * 32 + q * 8];
      short8_t ah = (g == 0) ? ah0 : ahn[g - 1];
      acc[tt] = __builtin_amdgcn_mfma_f32_16x16x32_bf16(ah, bh, acc[tt], 0, 0, 0);
      acc[tt] = __builtin_amdgcn_mfma_f32_16x16x32_bf16(ah, bl, acc[tt], 0, 0, 0);
      if (g == 0)  // lo-plane only for self (means are hi-only)
        acc[tt] = __builtin_amdgcn_mfma_f32_16x16x32_bf16(al0, bh, acc[tt], 0, 0, 0);
    }
  }
#pragma unroll
  for (int tt = 0; tt < 4; tt++) {
    float bia = bias[16 * tt + m_];
#pragma unroll
    for (int reg = 0; reg < 4; reg++) {
      int node = n0 + q * 4 + reg;
      if (node < N) {
        float val = fmaxf(acc[tt][reg] + bia, 0.f);
        short hh = f2bf(val);
        h1h[(size_t)node * HID + 16 * tt + m_] = hh;
        h1l[(size_t)node * HID + 16 * tt + m_] = f2bf(val - bf2f(hh));
      }
    }
  }
}

// ====== layer-2 GEMM: streaming A (h1 self + agg2 means) + MFMA + pooled epilogue ======
__global__ __launch_bounds__(256) void l2gemm_k(
    const short* __restrict__ h1h, const short* __restrict__ h1l, const short* __restrict__ agg,
    const short* __restrict__ wth, const short* __restrict__ wtl,
    const float* __restrict__ bias, const float* __restrict__ linW,
    const int* __restrict__ batch, float* __restrict__ gs, float* __restrict__ gc, int N) {
  const int t = threadIdx.x;
  const int lane = t & 63, w = t >> 6;
  const int m_ = lane & 15, q = lane >> 4;
  const int n0 = blockIdx.x * 64 + w * 16;
  int n = n0 + m_;
  if (n >= N) n = N - 1;

  f32x4 acc[4];
#pragma unroll
  for (int i = 0; i < 4; i++) acc[i] = (f32x4){0.f, 0.f, 0.f, 0.f};

  // self (k 0..63), hi+lo
  {
    short8_t ah[2], al[2];
#pragma unroll
    for (int s_ = 0; s_ < 2; s_++) {
      ah[s_] = *(const short8_t*)&h1h[(size_t)n * HID + s_ * 32 + q * 8];
      al[s_] = *(const short8_t*)&h1l[(size_t)n * HID + s_ * 32 + q * 8];
    }
#pragma unroll
    for (int tt = 0; tt < 4; tt++) {
      const size_t wrow = (size_t)(16 * tt + m_) * 256;
#pragma unroll
      for (int s_ = 0; s_ < 2; s_++) {
        short8_t bh = *(const short8_t*)&wth[wrow + s_ * 32 + q * 8];
        short8_t bl = *(const short8_t*)&wtl[wrow + s_ * 32 + q * 8];
        acc[tt] = __builtin_amdgcn_mfma_f32_16x16x32_bf16(ah[s_], bh, acc[tt], 0, 0, 0);
        acc[tt] = __builtin_amdgcn_mfma_f32_16x16x32_bf16(ah[s_], bl, acc[tt], 0, 0, 0);
        acc[tt] = __builtin_amdgcn_mfma_f32_16x16x32_bf16(al[s_], bh, acc[tt], 0, 0, 0);
      }
    }
  }
  // relation means from agg2 (hi only), coalesced streaming loads
#pragma unroll
  for (int r = 0; r < NREL; r++) {
    short8_t ah[2];
#pragma unroll
    for (int s_ = 0; s_ < 2; s_++)
      ah[s_] = *(const short8_t*)&agg[((size_t)r * N + n) * HID + s_ * 32 + q * 8];
#pragma unroll
    for (int tt = 0; tt < 4; tt++) {
      const size_t wrow = (size_t)(16 * tt + m_) * 256;
#pragma unroll
      for (int s_ = 0; s_ < 2; s_++) {
        short8_t bh = *(const short8_t*)&wth[wrow + (1 + r) * 64 + s_ * 32 + q * 8];
        short8_t bl = *(const short8_t*)&wtl[wrow + (1 + r) * 64 + s_ * 32 + q * 8];
        acc[tt] = __builtin_amdgcn_mfma_f32_16x16x32_bf16(ah[s_], bh, acc[tt], 0, 0, 0);
        acc[tt] = __builtin_amdgcn_mfma_f32_16x16x32_bf16(ah[s_], bl, acc[tt], 0, 0, 0);
      }
    }
  }
  // pooled epilogue
  float bia[4], lw0[4], lw1[4];
#pragma unroll
  for (int tt = 0; tt < 4; tt++) {
    int col = 16 * tt + m_;
    bia[tt] = bias[col];
    lw0[tt] = linW[col * 2 + 0];
    lw1[tt] = linW[col * 2 + 1];
  }
#pragma unroll
  for (int reg = 0; reg < 4; reg++) {
    int node = n0 + q * 4 + reg;
    float p0 = 0.f, p1 = 0.f;
#pragma unroll
    for (int tt = 0; tt < 4; tt++) {
      float v = fmaxf(acc[tt][reg] + bia[tt], 0.f);
      p0 += v * lw0[tt];
      p1 += v * lw1[tt];
    }
#pragma unroll
    for (int o = 1; o < 16; o <<= 1) {
      p0 += __shfl_xor(p0, o, 64);
      p1 += __shfl_xor(p1, o, 64);
    }
    if (m_ == 0 && node < N) {
      int g = batch[node];
      atomicAdd(&gs[g * 2 + 0], p0);
      atomicAdd(&gs[g * 2 + 1], p1);
      atomicAdd(&gc[g], 1.0f);
    }
  }
}

__global__ __launch_bounds__(256) void final_k(const float* __restrict__ gs,
                                               const float* __restrict__ gc,
                                               const float* __restrict__ linb,
                                               float* __restrict__ out, int G) {
  int i = blockIdx.x * 256 + threadIdx.x;
  if (i >= G * 2) return;
  int g = i >> 1, o = i & 1;
  out[i] = gs[i] / fmaxf(gc[g], 1.0f) + linb[o];
}

extern "C" void kernel_launch(void* const* d_in, const int* in_sizes, int n_in,
                              void* d_out, int out_size, void* d_ws, size_t ws_size,
                              hipStream_t stream) {
  const int* sid = (const int*)d_in[0];
  const int* cid = (const int*)d_in[1];
  const int* pid = (const int*)d_in[2];
  const int* ei = (const int*)d_in[3];
  const int* et = (const int*)d_in[4];
  const int* batch = (const int*)d_in[5];
  const float* se = (const float*)d_in[7];
  const float* ce = (const float*)d_in[8];
  const float* pe = (const float*)d_in[9];
  const float* W1 = (const float*)d_in[10];
  const float* root1 = (const float*)d_in[11];
  const float* b1 = (const float*)d_in[12];
  const float* W2 = (const float*)d_in[13];
  const float* root2 = (const float*)d_in[14];
  const float* b2 = (const float*)d_in[15];
  const float* linW = (const float*)d_in[16];
  const float* linb = (const float*)d_in[17];
  float* out = (float*)d_out;

  const int N = in_sizes[0];
  const int E = in_sizes[4];
  const int G = out_size / 2;
  const int* src = ei;
  const int* dst = ei + E;
  const int M = N * NREL;
  const int P = (M + 1023) / 1024;

  // ---- workspace layout (peak ~248 MB; 16B-aligned blocks) ----
  char* w = (char*)d_ws;
  short* h1h = (short*)w;  w += (size_t)N * HID * sizeof(short);
  short* h1l = (short*)w;  w += (size_t)N * HID * sizeof(short);
  short* xh = (short*)w;   w += (size_t)N * EMB * sizeof(short);
  short* xl = (short*)w;   w += (size_t)N * EMB * sizeof(short);
  float* gs = (float*)w;   w += (size_t)G * 2 * sizeof(float);
  float* gc = (float*)w;   w += (size_t)G * sizeof(float);
  int* icnt = (int*)w;     w += (size_t)M * sizeof(int);
  int* offs = (int*)w;     w += (size_t)M * sizeof(int);
  int* cursor = (int*)w;   w += (size_t)M * sizeof(int);
  int* csr = (int*)w;      w += ((size_t)E + 12) * sizeof(int);  // pad for idx bursts
  short* w1h = (short*)w;  w += (size_t)64 * 128 * sizeof(short);
  short* w1l = (short*)w;  w += (size_t)64 * 128 * sizeof(short);
  short* w2h = (short*)w;  w += (size_t)64 * 256 * sizeof(short);
  short* w2l = (short*)w;  w += (size_t)64 * 256 * sizeof(short);
  short* aggb = (short*)w; w += (size_t)M * HID * sizeof(short);  // reused: l1 (M*32) then l2 (M*64)
  int* psum = (int*)w;     w += (size_t)P * sizeof(int);
  if ((size_t)(w - (char*)d_ws) > ws_size) return;  // fail loudly, no OOB

  hipMemsetAsync(icnt, 0, (size_t)M * sizeof(int), stream);
  hipMemsetAsync(gs, 0, (size_t)G * 3 * sizeof(float), stream);

  int prep_n = N * 8;
  if (prep_n < E) prep_n = E;
  if (prep_n < 64 * 256) prep_n = 64 * 256;
  prep_k<<<(prep_n + 255) / 256, 256, 0, stream>>>(sid, cid, pid, se, ce, pe, xh, xl, dst, et,
                                                   icnt, root1, W1, root2, W2, w1h, w1l, w2h,
                                                   w2l, N, E);
  scan1_k<<<P, 256, 0, stream>>>(icnt, psum, M);
  scan2_k<<<1, 256, 0, stream>>>(psum, P);
  scan3_k<<<P, 256, 0, stream>>>(icnt, psum, offs, cursor, M);
  scatter_k<<<(E + 255) / 256, 256, 0, stream>>>(src, dst, et, cursor, csr, E, N);

  int blocks = (N + 63) / 64;
  l1agg_k<<<(unsigned)(((size_t)M * 4 + 255) / 256), 256, 0, stream>>>(xh, offs, icnt, csr,
                                                                       aggb, M);
  l1gemm_k<<<blocks, 256, 0, stream>>>(xh, xl, aggb, w1h, w1l, b1, h1h, h1l, N);
  l2agg_k<<<(unsigned)(((size_t)M * 8 + 255) / 256), 256, 0, stream>>>(h1h, offs, icnt, csr,
                                                                       aggb, M);
  l2gemm_k<<<blocks, 256, 0, stream>>>(h1h, h1l, aggb, w2h, w2l, b2, linW, batch, gs, gc, N);
  final_k<<<(G * 2 + 255) / 256, 256, 0, stream>>>(gs, gc, linb, out, G);
}

// Round 16
// 618.535 us; speedup vs baseline: 1.0144x; 1.0144x over previous
//
#include <hip/hip_runtime.h>
#include <hip/hip_bf16.h>

#define NREL 3
#define EMB 32
#define HID 64

typedef __attribute__((ext_vector_type(8))) short short8_t;
typedef __attribute__((ext_vector_type(4))) short short4_t;
typedef __attribute__((ext_vector_type(4))) float f32x4;

__device__ inline short f2bf(float v) {
  __hip_bfloat16 b = __float2bfloat16(v);
  short s;
  __builtin_memcpy(&s, &b, 2);
  return s;
}
__device__ inline float bf2f(short s) {
  __hip_bfloat16 b;
  __builtin_memcpy(&b, &s, 2);
  return __bfloat162float(b);
}

// ---- fused prep: embedding (hi/lo planes) + edge histogram + weight prep ----
__global__ __launch_bounds__(256) void prep_k(
    const int* __restrict__ sid, const int* __restrict__ cid, const int* __restrict__ pid,
    const float* __restrict__ se, const float* __restrict__ ce, const float* __restrict__ pe,
    short* __restrict__ xh, short* __restrict__ xl,
    const int* __restrict__ dst, const int* __restrict__ et, int* __restrict__ icnt,
    const float* __restrict__ root1, const float* __restrict__ W1,
    const float* __restrict__ root2, const float* __restrict__ W2,
    short* __restrict__ w1h, short* __restrict__ w1l,
    short* __restrict__ w2h, short* __restrict__ w2l, int N, int E) {
  int i = blockIdx.x * 256 + threadIdx.x;
  if (i < N * 8) {
    int n = i >> 3, cg = i & 7;
    const float4 a = *(const float4*)&se[sid[n] * EMB + cg * 4];
    const float4 b = *(const float4*)&ce[cid[n] * EMB + cg * 4];
    const float4 c = *(const float4*)&pe[pid[n] * EMB + cg * 4];
    float v[4];
    v[0] = a.x + b.x + c.x; v[1] = a.y + b.y + c.y;
    v[2] = a.z + b.z + c.z; v[3] = a.w + b.w + c.w;
    short4_t h, l;
#pragma unroll
    for (int j = 0; j < 4; j++) {
      short hh = f2bf(v[j]);
      h[j] = hh;
      l[j] = f2bf(v[j] - bf2f(hh));
    }
    *(short4_t*)&xh[(size_t)n * EMB + cg * 4] = h;
    *(short4_t*)&xl[(size_t)n * EMB + cg * 4] = l;
  }
  if (i < E) atomicAdd(&icnt[et[i] * N + dst[i]], 1);
  if (i < 64 * 128) {
    int k = i >> 6, n = i & 63;
    float v = (k < EMB) ? root1[k * 64 + n] : W1[(k - EMB) * 64 + n];
    short h = f2bf(v);
    w1h[n * 128 + k] = h;
    w1l[n * 128 + k] = f2bf(v - bf2f(h));
  }
  if (i < 64 * 256) {
    int k = i >> 6, n = i & 63;
    float v = (k < HID) ? root2[k * 64 + n] : W2[(k - HID) * 64 + n];
    short h = f2bf(v);
    w2h[n * 256 + k] = h;
    w2l[n * 256 + k] = f2bf(v - bf2f(h));
  }
}

// ---- graph offsets from sorted batch: goff[g] = first node of graph g; goff[G] = N ----
__global__ __launch_bounds__(256) void goff_k(const int* __restrict__ batch,
                                              int* __restrict__ goff, int N, int G) {
  int n = blockIdx.x * 256 + threadIdx.x;
  if (n >= N) return;
  int cur = batch[n];
  int prev = (n == 0) ? -1 : batch[n - 1];
  for (int g = prev + 1; g <= cur; g++) goff[g] = n;
  if (n == N - 1)
    for (int g = cur + 1; g <= G; g++) goff[g] = N;
}

__global__ __launch_bounds__(256) void scan1_k(const int* __restrict__ icnt,
                                               int* __restrict__ psum, int M) {
  int base = blockIdx.x * 1024 + threadIdx.x * 4;
  int s = 0;
#pragma unroll
  for (int j = 0; j < 4; j++) {
    int i = base + j;
    if (i < M) s += icnt[i];
  }
  __shared__ int tmp[256];
  tmp[threadIdx.x] = s;
  __syncthreads();
  for (int off = 128; off > 0; off >>= 1) {
    if (threadIdx.x < off) tmp[threadIdx.x] += tmp[threadIdx.x + off];
    __syncthreads();
  }
  if (threadIdx.x == 0) psum[blockIdx.x] = tmp[0];
}

__global__ __launch_bounds__(256) void scan2_k(int* __restrict__ psum, int P) {
  __shared__ int tmp[256];
  __shared__ int carry_s;
  if (threadIdx.x == 0) carry_s = 0;
  __syncthreads();
  for (int base = 0; base < P; base += 256) {
    int i = base + threadIdx.x;
    int v = (i < P) ? psum[i] : 0;
    tmp[threadIdx.x] = v;
    __syncthreads();
    for (int off = 1; off < 256; off <<= 1) {
      int u = (threadIdx.x >= off) ? tmp[threadIdx.x - off] : 0;
      __syncthreads();
      tmp[threadIdx.x] += u;
      __syncthreads();
    }
    int carry = carry_s;
    if (i < P) psum[i] = carry + tmp[threadIdx.x] - v;
    __syncthreads();
    if (threadIdx.x == 0) carry_s = carry + tmp[255];
    __syncthreads();
  }
}

__global__ __launch_bounds__(256) void scan3_k(const int* __restrict__ icnt,
                                               const int* __restrict__ psum,
                                               int* __restrict__ offs,
                                               int* __restrict__ cursor, int M) {
  int base = blockIdx.x * 1024 + threadIdx.x * 4;
  int v[4];
  int s = 0;
#pragma unroll
  for (int j = 0; j < 4; j++) {
    int i = base + j;
    v[j] = (i < M) ? icnt[i] : 0;
    s += v[j];
  }
  __shared__ int tmp[256];
  tmp[threadIdx.x] = s;
  __syncthreads();
  for (int off = 1; off < 256; off <<= 1) {
    int u = (threadIdx.x >= off) ? tmp[threadIdx.x - off] : 0;
    __syncthreads();
    tmp[threadIdx.x] += u;
    __syncthreads();
  }
  int run = psum[blockIdx.x] + tmp[threadIdx.x] - s;
#pragma unroll
  for (int j = 0; j < 4; j++) {
    int i = base + j;
    if (i < M) {
      offs[i] = run;
      cursor[i] = run;
      run += v[j];
    }
  }
}

__global__ __launch_bounds__(256) void scatter_k(const int* __restrict__ src,
                                                 const int* __restrict__ dst,
                                                 const int* __restrict__ et,
                                                 int* __restrict__ cursor,
                                                 int* __restrict__ csr, int E, int N) {
  int e = blockIdx.x * 256 + threadIdx.x;
  if (e >= E) return;
  int p = atomicAdd(&cursor[et[e] * N + dst[e]], 1);
  csr[p] = src[e];
}

// ====== dedicated high-occupancy gather kernels (thread = segment x 16B slice) ======
__global__ __launch_bounds__(256) void l1agg_k(
    const short* __restrict__ xh, const int* __restrict__ offs, const int* __restrict__ icnt,
    const int* __restrict__ csr, short* __restrict__ agg, int SEG) {
  int tid = blockIdx.x * 256 + threadIdx.x;
  if (tid >= SEG * 4) return;
  int q = tid & 3, seg = tid >> 2;
  int beg = offs[seg], len = icnt[seg];
  int i0 = csr[beg], i1 = csr[beg + 1], i2 = csr[beg + 2], i3 = csr[beg + 3];
  short8_t v0 = {0,0,0,0,0,0,0,0}, v1 = v0, v2 = v0, v3 = v0;
  if (0 < len) v0 = *(const short8_t*)&xh[(size_t)i0 * EMB + q * 8];
  if (1 < len) v1 = *(const short8_t*)&xh[(size_t)i1 * EMB + q * 8];
  if (2 < len) v2 = *(const short8_t*)&xh[(size_t)i2 * EMB + q * 8];
  if (3 < len) v3 = *(const short8_t*)&xh[(size_t)i3 * EMB + q * 8];
  float a[8];
#pragma unroll
  for (int i = 0; i < 8; i++) a[i] = bf2f(v0[i]) + bf2f(v1[i]) + bf2f(v2[i]) + bf2f(v3[i]);
  for (int j = 4; j < len; j++) {
    int id = csr[beg + j];
    short8_t v = *(const short8_t*)&xh[(size_t)id * EMB + q * 8];
#pragma unroll
    for (int i = 0; i < 8; i++) a[i] += bf2f(v[i]);
  }
  float inv = 1.f / fmaxf((float)len, 1.f);
  short8_t o;
#pragma unroll
  for (int i = 0; i < 8; i++) o[i] = f2bf(a[i] * inv);
  *(short8_t*)&agg[(size_t)seg * EMB + q * 8] = o;
}

__global__ __launch_bounds__(256) void l2agg_k(
    const short* __restrict__ h1h, const int* __restrict__ offs, const int* __restrict__ icnt,
    const int* __restrict__ csr, short* __restrict__ agg, int SEG) {
  int tid = blockIdx.x * 256 + threadIdx.x;
  if (tid >= SEG * 8) return;
  int q = tid & 7, seg = tid >> 3;
  int beg = offs[seg], len = icnt[seg];
  int i0 = csr[beg], i1 = csr[beg + 1], i2 = csr[beg + 2], i3 = csr[beg + 3];
  short8_t v0 = {0,0,0,0,0,0,0,0}, v1 = v0, v2 = v0, v3 = v0;
  if (0 < len) v0 = *(const short8_t*)&h1h[(size_t)i0 * HID + q * 8];
  if (1 < len) v1 = *(const short8_t*)&h1h[(size_t)i1 * HID + q * 8];
  if (2 < len) v2 = *(const short8_t*)&h1h[(size_t)i2 * HID + q * 8];
  if (3 < len) v3 = *(const short8_t*)&h1h[(size_t)i3 * HID + q * 8];
  float a[8];
#pragma unroll
  for (int i = 0; i < 8; i++) a[i] = bf2f(v0[i]) + bf2f(v1[i]) + bf2f(v2[i]) + bf2f(v3[i]);
  for (int j = 4; j < len; j++) {
    int id = csr[beg + j];
    short8_t v = *(const short8_t*)&h1h[(size_t)id * HID + q * 8];
#pragma unroll
    for (int i = 0; i < 8; i++) a[i] += bf2f(v[i]);
  }
  float inv = 1.f / fmaxf((float)len, 1.f);
  short8_t o;
#pragma unroll
  for (int i = 0; i < 8; i++) o[i] = f2bf(a[i] * inv);
  *(short8_t*)&agg[(size_t)seg * HID + q * 8] = o;
}

// ====== layer-1 GEMM: streaming A + split-bf16 MFMA -> h1 hi/lo ======
__global__ __launch_bounds__(256) void l1gemm_k(
    const short* __restrict__ xh, const short* __restrict__ xl, const short* __restrict__ agg,
    const short* __restrict__ wth, const short* __restrict__ wtl,
    const float* __restrict__ bias, short* __restrict__ h1h, short* __restrict__ h1l, int N) {
  const int t = threadIdx.x;
  const int lane = t & 63, w = t >> 6;
  const int m_ = lane & 15, q = lane >> 4;
  const int n0 = blockIdx.x * 64 + w * 16;
  int n = n0 + m_;
  if (n >= N) n = N - 1;

  short8_t ah0 = *(const short8_t*)&xh[(size_t)n * EMB + q * 8];
  short8_t al0 = *(const short8_t*)&xl[(size_t)n * EMB + q * 8];
  short8_t ahn[NREL];
#pragma unroll
  for (int r = 0; r < NREL; r++)
    ahn[r] = *(const short8_t*)&agg[((size_t)r * N + n) * EMB + q * 8];

  f32x4 acc[4];
#pragma unroll
  for (int i = 0; i < 4; i++) acc[i] = (f32x4){0.f, 0.f, 0.f, 0.f};
#pragma unroll
  for (int tt = 0; tt < 4; tt++) {
    const size_t wrow = (size_t)(16 * tt + m_) * 128;
#pragma unroll
    for (int g = 0; g < 4; g++) {
      short8_t bh = *(const short8_t*)&wth[wrow + g * 32 + q * 8];
      short8_t bl = *(const short8_t*)&wtl[wrow + g * 32 + q * 8];
      short8_t ah = (g == 0) ? ah0 : ahn[g - 1];
      acc[tt] = __builtin_amdgcn_mfma_f32_16x16x32_bf16(ah, bh, acc[tt], 0, 0, 0);
      acc[tt] = __builtin_amdgcn_mfma_f32_16x16x32_bf16(ah, bl, acc[tt], 0, 0, 0);
      if (g == 0)
        acc[tt] = __builtin_amdgcn_mfma_f32_16x16x32_bf16(al0, bh, acc[tt], 0, 0, 0);
    }
  }
#pragma unroll
  for (int tt = 0; tt < 4; tt++) {
    float bia = bias[16 * tt + m_];
#pragma unroll
    for (int reg = 0; reg < 4; reg++) {
      int node = n0 + q * 4 + reg;
      if (node < N) {
        float val = fmaxf(acc[tt][reg] + bia, 0.f);
        short hh = f2bf(val);
        h1h[(size_t)node * HID + 16 * tt + m_] = hh;
        h1l[(size_t)node * HID + 16 * tt + m_] = f2bf(val - bf2f(hh));
      }
    }
  }
}

// ====== layer-2 GEMM: streaming A + MFMA + ATOMIC-FREE projection epilogue ======
__global__ __launch_bounds__(256) void l2gemm_k(
    const short* __restrict__ h1h, const short* __restrict__ h1l, const short* __restrict__ agg,
    const short* __restrict__ wth, const short* __restrict__ wtl,
    const float* __restrict__ bias, const float* __restrict__ linW,
    float* __restrict__ proj, int N) {
  const int t = threadIdx.x;
  const int lane = t & 63, w = t >> 6;
  const int m_ = lane & 15, q = lane >> 4;
  const int n0 = blockIdx.x * 64 + w * 16;
  int n = n0 + m_;
  if (n >= N) n = N - 1;

  f32x4 acc[4];
#pragma unroll
  for (int i = 0; i < 4; i++) acc[i] = (f32x4){0.f, 0.f, 0.f, 0.f};

  // self (k 0..63), hi+lo
  {
    short8_t ah[2], al[2];
#pragma unroll
    for (int s_ = 0; s_ < 2; s_++) {
      ah[s_] = *(const short8_t*)&h1h[(size_t)n * HID + s_ * 32 + q * 8];
      al[s_] = *(const short8_t*)&h1l[(size_t)n * HID + s_ * 32 + q * 8];
    }
#pragma unroll
    for (int tt = 0; tt < 4; tt++) {
      const size_t wrow = (size_t)(16 * tt + m_) * 256;
#pragma unroll
      for (int s_ = 0; s_ < 2; s_++) {
        short8_t bh = *(const short8_t*)&wth[wrow + s_ * 32 + q * 8];
        short8_t bl = *(const short8_t*)&wtl[wrow + s_ * 32 + q * 8];
        acc[tt] = __builtin_amdgcn_mfma_f32_16x16x32_bf16(ah[s_], bh, acc[tt], 0, 0, 0);
        acc[tt] = __builtin_amdgcn_mfma_f32_16x16x32_bf16(ah[s_], bl, acc[tt], 0, 0, 0);
        acc[tt] = __builtin_amdgcn_mfma_f32_16x16x32_bf16(al[s_], bh, acc[tt], 0, 0, 0);
      }
    }
  }
  // relation means from agg2 (hi only), streaming
#pragma unroll
  for (int r = 0; r < NREL; r++) {
    short8_t ah[2];
#pragma unroll
    for (int s_ = 0; s_ < 2; s_++)
      ah[s_] = *(const short8_t*)&agg[((size_t)r * N + n) * HID + s_ * 32 + q * 8];
#pragma unroll
    for (int tt = 0; tt < 4; tt++) {
      const size_t wrow = (size_t)(16 * tt + m_) * 256;
#pragma unroll
      for (int s_ = 0; s_ < 2; s_++) {
        short8_t bh = *(const short8_t*)&wth[wrow + (1 + r) * 64 + s_ * 32 + q * 8];
        short8_t bl = *(const short8_t*)&wtl[wrow + (1 + r) * 64 + s_ * 32 + q * 8];
        acc[tt] = __builtin_amdgcn_mfma_f32_16x16x32_bf16(ah[s_], bh, acc[tt], 0, 0, 0);
        acc[tt] = __builtin_amdgcn_mfma_f32_16x16x32_bf16(ah[s_], bl, acc[tt], 0, 0, 0);
      }
    }
  }
  // epilogue: bias+relu, 64->2 projection, reduce across m_ lanes, plain stores
  float bia[4], lw0[4], lw1[4];
#pragma unroll
  for (int tt = 0; tt < 4; tt++) {
    int col = 16 * tt + m_;
    bia[tt] = bias[col];
    lw0[tt] = linW[col * 2 + 0];
    lw1[tt] = linW[col * 2 + 1];
  }
#pragma unroll
  for (int reg = 0; reg < 4; reg++) {
    int node = n0 + q * 4 + reg;
    float p0 = 0.f, p1 = 0.f;
#pragma unroll
    for (int tt = 0; tt < 4; tt++) {
      float v = fmaxf(acc[tt][reg] + bia[tt], 0.f);
      p0 += v * lw0[tt];
      p1 += v * lw1[tt];
    }
#pragma unroll
    for (int o = 1; o < 16; o <<= 1) {
      p0 += __shfl_xor(p0, o, 64);
      p1 += __shfl_xor(p1, o, 64);
    }
    if (m_ == 0 && node < N) {
      float2 pv = {p0, p1};
      *(float2*)&proj[(size_t)node * 2] = pv;
    }
  }
}

// ---- pool: one thread per graph, contiguous node range (batch sorted) ----
__global__ __launch_bounds__(256) void pool_k(const float* __restrict__ proj,
                                              const int* __restrict__ goff,
                                              const float* __restrict__ linb,
                                              float* __restrict__ out, int G) {
  int g = blockIdx.x * 256 + threadIdx.x;
  if (g >= G) return;
  int a = goff[g], b = goff[g + 1];
  float s0 = 0.f, s1 = 0.f;
  for (int n = a; n < b; n++) {
    float2 pv = *(const float2*)&proj[(size_t)n * 2];
    s0 += pv.x;
    s1 += pv.y;
  }
  float c = fmaxf((float)(b - a), 1.f);
  out[g * 2 + 0] = s0 / c + linb[0];
  out[g * 2 + 1] = s1 / c + linb[1];
}

extern "C" void kernel_launch(void* const* d_in, const int* in_sizes, int n_in,
                              void* d_out, int out_size, void* d_ws, size_t ws_size,
                              hipStream_t stream) {
  const int* sid = (const int*)d_in[0];
  const int* cid = (const int*)d_in[1];
  const int* pid = (const int*)d_in[2];
  const int* ei = (const int*)d_in[3];
  const int* et = (const int*)d_in[4];
  const int* batch = (const int*)d_in[5];
  const float* se = (const float*)d_in[7];
  const float* ce = (const float*)d_in[8];
  const float* pe = (const float*)d_in[9];
  const float* W1 = (const float*)d_in[10];
  const float* root1 = (const float*)d_in[11];
  const float* b1 = (const float*)d_in[12];
  const float* W2 = (const float*)d_in[13];
  const float* root2 = (const float*)d_in[14];
  const float* b2 = (const float*)d_in[15];
  const float* linW = (const float*)d_in[16];
  const float* linb = (const float*)d_in[17];
  float* out = (float*)d_out;

  const int N = in_sizes[0];
  const int E = in_sizes[4];
  const int G = out_size / 2;
  const int* src = ei;
  const int* dst = ei + E;
  const int M = N * NREL;
  const int P = (M + 1023) / 1024;

  // ---- workspace layout (peak ~252 MB; 16B-aligned blocks) ----
  char* w = (char*)d_ws;
  short* h1h = (short*)w;  w += (size_t)N * HID * sizeof(short);
  short* h1l = (short*)w;  w += (size_t)N * HID * sizeof(short);
  short* xh = (short*)w;   w += (size_t)N * EMB * sizeof(short);
  short* xl = (short*)w;   w += (size_t)N * EMB * sizeof(short);
  float* proj = (float*)w; w += (size_t)N * 2 * sizeof(float);
  int* goff = (int*)w;     w += ((size_t)G + 1) * sizeof(int);
  int* icnt = (int*)w;     w += (size_t)M * sizeof(int);
  int* offs = (int*)w;     w += (size_t)M * sizeof(int);
  int* cursor = (int*)w;   w += (size_t)M * sizeof(int);
  int* csr = (int*)w;      w += ((size_t)E + 12) * sizeof(int);  // pad for idx bursts
  short* w1h = (short*)w;  w += (size_t)64 * 128 * sizeof(short);
  short* w1l = (short*)w;  w += (size_t)64 * 128 * sizeof(short);
  short* w2h = (short*)w;  w += (size_t)64 * 256 * sizeof(short);
  short* w2l = (short*)w;  w += (size_t)64 * 256 * sizeof(short);
  short* aggb = (short*)w; w += (size_t)M * HID * sizeof(short);  // reused l1 (M*32) / l2 (M*64)
  int* psum = (int*)w;     w += (size_t)P * sizeof(int);
  if ((size_t)(w - (char*)d_ws) > ws_size) return;  // fail loudly, no OOB

  hipMemsetAsync(icnt, 0, (size_t)M * sizeof(int), stream);

  int prep_n = N * 8;
  if (prep_n < E) prep_n = E;
  if (prep_n < 64 * 256) prep_n = 64 * 256;
  prep_k<<<(prep_n + 255) / 256, 256, 0, stream>>>(sid, cid, pid, se, ce, pe, xh, xl, dst, et,
                                                   icnt, root1, W1, root2, W2, w1h, w1l, w2h,
                                                   w2l, N, E);
  goff_k<<<(N + 255) / 256, 256, 0, stream>>>(batch, goff, N, G);
  scan1_k<<<P, 256, 0, stream>>>(icnt, psum, M);
  scan2_k<<<1, 256, 0, stream>>>(psum, P);
  scan3_k<<<P, 256, 0, stream>>>(icnt, psum, offs, cursor, M);
  scatter_k<<<(E + 255) / 256, 256, 0, stream>>>(src, dst, et, cursor, csr, E, N);

  int blocks = (N + 63) / 64;
  l1agg_k<<<(unsigned)(((size_t)M * 4 + 255) / 256), 256, 0, stream>>>(xh, offs, icnt, csr,
                                                                       aggb, M);
  l1gemm_k<<<blocks, 256, 0, stream>>>(xh, xl, aggb, w1h, w1l, b1, h1h, h1l, N);
  l2agg_k<<<(unsigned)(((size_t)M * 8 + 255) / 256), 256, 0, stream>>>(h1h, offs, icnt, csr,
                                                                       aggb, M);
  l2gemm_k<<<blocks, 256, 0, stream>>>(h1h, h1l, aggb, w2h, w2l, b2, linW, proj, N);
  pool_k<<<(G + 255) / 256, 256, 0, stream>>>(proj, goff, linb, out, G);
}